// Round 1
// baseline (764.051 us; speedup 1.0000x reference)
//
#include <hip/hip_runtime.h>
#include <stdint.h>

#define N_TOK 4096
#define QDIM  1024
#define CDIM  1024
#define NH    8
#define DH    64
#define INNER 512
#define BATCH 2
#define N1    4097   // keys incl. background row
#define N1P   4128   // padded to /32

typedef __attribute__((ext_vector_type(8))) short short8;
typedef __attribute__((ext_vector_type(4))) float f32x4;

__device__ __forceinline__ short f2bf(float f) {
    union { float f; uint32_t u; } x; x.f = f;
    uint32_t r = x.u + 0x7fffu + ((x.u >> 16) & 1u);   // RNE
    return (short)(r >> 16);
}

__device__ __forceinline__ void async_copy16(void* lds, const void* g) {
    __builtin_amdgcn_global_load_lds(
        (const __attribute__((address_space(1))) void*)g,
        (__attribute__((address_space(3))) void*)lds, 16, 0, 0);
}

// ---------------- cast fp32 -> bf16 (vectorized) ----------------
__global__ __launch_bounds__(256) void cast_bf16_kernel(
        const float* __restrict__ s, short* __restrict__ d, int n4) {
    int i = blockIdx.x * 256 + threadIdx.x;
    if (i >= n4) return;
    float4 v = ((const float4*)s)[i];
    short4 o = make_short4(f2bf(v.x), f2bf(v.y), f2bf(v.z), f2bf(v.w));
    ((short4*)d)[i] = o;
}

// ------------- weight transpose-cast: W[K][N] f32 -> Wt[N][K] bf16 -------------
__global__ __launch_bounds__(256) void transpose_cast_kernel(
        const float* __restrict__ W, short* __restrict__ Wt, int K, int N) {
    __shared__ float tile[32][33];
    int n0 = blockIdx.x * 32, k0 = blockIdx.y * 32;
    int tx = threadIdx.x & 31, ty = threadIdx.x >> 5;       // ty 0..7
    for (int r = ty; r < 32; r += 8)
        tile[r][tx] = W[(size_t)(k0 + r) * N + n0 + tx];
    __syncthreads();
    for (int r = ty; r < 32; r += 8)
        Wt[(size_t)(n0 + r) * K + k0 + tx] = f2bf(tile[tx][r]);
}

// ---------------- pooled mean stage 1: partial sums over 128-row chunks ----------------
__global__ __launch_bounds__(256) void pool_partial_kernel(
        const float* __restrict__ x, float* __restrict__ part) {
    int b = blockIdx.y, c = blockIdx.x;                     // c 0..31
    int t = threadIdx.x;
    float s0 = 0.f, s1 = 0.f, s2 = 0.f, s3 = 0.f;
    const float* xp = x + ((size_t)b * N_TOK + c * 128) * QDIM;
    for (int n = 0; n < 128; n++) {
        const float* row = xp + (size_t)n * QDIM;
        s0 += row[t];
        s1 += row[256 + t];
        s2 += row[512 + t];
        s3 += row[768 + t];
    }
    float* pp = part + ((size_t)b * 32 + c) * QDIM;
    pp[t] = s0; pp[256 + t] = s1; pp[512 + t] = s2; pp[768 + t] = s3;
}

// ------- stage 2: finish mean, fp32 bg projections, write bg row + zero pads -------
__global__ __launch_bounds__(256) void bg_kernel(
        const float* __restrict__ part, const float* __restrict__ Wkbg,
        const float* __restrict__ Wvbg, short* __restrict__ kb, short* __restrict__ vb) {
    int b = blockIdx.x, t = threadIdx.x;
    __shared__ float pooled[QDIM];
    for (int d = t; d < QDIM; d += 256) {
        float s = 0.f;
        for (int c = 0; c < 32; c++) s += part[((size_t)b * 32 + c) * QDIM + d];
        pooled[d] = s * (1.f / (float)N_TOK);
    }
    __syncthreads();
    for (int o = t; o < INNER; o += 256) {
        float sk = 0.f, sv = 0.f;
        for (int k = 0; k < QDIM; k++) {
            float p = pooled[k];
            sk += p * Wkbg[(size_t)k * INNER + o];
            sv += p * Wvbg[(size_t)k * INNER + o];
        }
        int h = o >> 6, d = o & 63;
        kb[(((size_t)(b * NH + h)) * N1P + N_TOK) * DH + d] = f2bf(sk);
        vb[(((size_t)(b * NH + h)) * N1P + N_TOK) * DH + d] = f2bf(sv);
    }
    // zero the padding key rows 4097..4127 for every head of this batch
    for (int idx = t; idx < NH * 31 * DH; idx += 256) {
        int h = idx / (31 * DH);
        int r = idx % (31 * DH);
        int j = N_TOK + 1 + r / DH;
        int d = r % DH;
        kb[(((size_t)(b * NH + h)) * N1P + j) * DH + d] = 0;
        vb[(((size_t)(b * NH + h)) * N1P + j) * DH + d] = 0;
    }
}

// ------- V transpose: [BH][N1P][64] bf16 -> [BH][64][N1P] bf16 -------
__global__ __launch_bounds__(256) void transpose_v_kernel(
        const short* __restrict__ vin, short* __restrict__ vout) {
    __shared__ short tile[32][65];
    int bh = blockIdx.z;
    int j0 = blockIdx.x * 32;
    int tx = threadIdx.x & 63, ty = threadIdx.x >> 6;       // ty 0..3
    const short* src = vin + (size_t)bh * N1P * DH;
    for (int r = ty; r < 32; r += 4)
        tile[r][tx] = src[(size_t)(j0 + r) * DH + tx];
    __syncthreads();
    int tc = threadIdx.x & 31, dy = threadIdx.x >> 5;       // dy 0..7
    short* dst = vout + (size_t)bh * DH * N1P;
    for (int d = dy; d < DH; d += 8)
        dst[(size_t)d * N1P + j0 + tc] = tile[tc][d];
}

// ---------------- bf16 MFMA GEMM: C[M,N] = A[M,K] @ Wt[N,K]^T ----------------
// 128x128 tile, BK=32, 4 waves (2x2), each wave 4x4 frags of 16x16x32.
// MODE 0: store bf16 [B,H,4096,64]; MODE 1: store bf16 [B,H,N1P,64];
// MODE 2: store f32 out[m*1024+n] + bias[n].
template <int MODE>
__global__ __launch_bounds__(256) void gemm_kernel(
        const short* __restrict__ A, const short* __restrict__ Wt,
        short* __restrict__ dstb, float* __restrict__ outf,
        const float* __restrict__ bias, int M, int K) {
    __shared__ short As[128 * 32];
    __shared__ short Bs[128 * 32];
    const int t = threadIdx.x;
    const int lane = t & 63, w = t >> 6;
    const int wr = w >> 1, wc = w & 1;
    const int lo = lane & 15, g = lane >> 4;
    const int m0 = blockIdx.x * 128, n0 = blockIdx.y * 128;
    const int arow = lane >> 2;          // row within 16-row segment
    const int ac8 = (lane & 3) * 8;      // 8-elem column chunk

    f32x4 acc[4][4] = {};

    for (int k0 = 0; k0 < K; k0 += 32) {
        for (int q = 0; q < 2; q++) {
            int seg = w * 2 + q;
            async_copy16(&As[seg * 512],
                         A + (size_t)(m0 + seg * 16 + arow) * K + k0 + ac8);
            async_copy16(&Bs[seg * 512],
                         Wt + (size_t)(n0 + seg * 16 + arow) * K + k0 + ac8);
        }
        __syncthreads();
        short8 af[4], bfv[4];
        for (int i = 0; i < 4; i++)
            af[i] = *(const short8*)&As[(wr * 64 + i * 16 + lo) * 32 + g * 8];
        for (int j = 0; j < 4; j++)
            bfv[j] = *(const short8*)&Bs[(wc * 64 + j * 16 + lo) * 32 + g * 8];
        for (int i = 0; i < 4; i++)
            for (int j = 0; j < 4; j++)
                acc[i][j] = __builtin_amdgcn_mfma_f32_16x16x32_bf16(
                    af[i], bfv[j], acc[i][j], 0, 0, 0);
        __syncthreads();
    }

    for (int i = 0; i < 4; i++)
        for (int j = 0; j < 4; j++) {
            int row = m0 + wr * 64 + i * 16 + g * 4;
            int col = n0 + wc * 64 + j * 16 + lo;
            f32x4 v = acc[i][j];
            for (int r = 0; r < 4; r++) {
                int m = row + r;
                if constexpr (MODE == 0) {
                    int b = m >> 12, ii = m & 4095, h = col >> 6, d = col & 63;
                    dstb[(((size_t)(b * NH + h)) * N_TOK + ii) * DH + d] = f2bf(v[r]);
                } else if constexpr (MODE == 1) {
                    int b = m >> 12, ii = m & 4095, h = col >> 6, d = col & 63;
                    dstb[(((size_t)(b * NH + h)) * N1P + ii) * DH + d] = f2bf(v[r]);
                } else {
                    outf[(size_t)m * QDIM + col] = v[r] + bias[col];
                }
            }
        }
}

// ---------------- flash attention ----------------
// grid (N/64, H, B), 256 threads; wave w owns 16 Q rows.
__global__ __launch_bounds__(256) void attn_kernel(
        const short* __restrict__ qb,   // [B,H,4096,64]
        const short* __restrict__ kb,   // [B,H,N1P,64]
        const short* __restrict__ vtb,  // [B,H,64,N1P]
        const int* __restrict__ mask,   // [B,4097]
        short* __restrict__ ob) {       // [B*4096, 512]
    const int t = threadIdx.x, lane = t & 63, w = t >> 6;
    const int lo = lane & 15, g = lane >> 4;
    const int b = blockIdx.z, h = blockIdx.y;
    const int q0 = blockIdx.x * 64 + w * 16;
    const size_t bh = (size_t)(b * NH + h);

    const short* qp = qb + (bh * N_TOK + q0 + lo) * DH;
    short8 qa0 = *(const short8*)(qp + g * 8);
    short8 qa1 = *(const short8*)(qp + 32 + g * 8);

    const short* kpB = kb + bh * N1P * DH;
    const short* vpB = vtb + bh * DH * N1P;
    const int* mrow = mask + b * N1;

    f32x4 o0 = {}, o1 = {}, o2 = {}, o3 = {};
    float m_r[4], l_r[4];
    for (int r = 0; r < 4; r++) { m_r[r] = -1e30f; l_r[r] = 0.f; }

    __shared__ short plds[4][16][32];
    f32x4 z = {};

    for (int j0 = 0; j0 < N1P; j0 += 32) {
        int jc0 = j0 + lo, jc1 = j0 + 16 + lo;
        bool mk0 = (jc0 < N1) && (mrow[min(jc0, N1 - 1)] != 0);
        bool mk1 = (jc1 < N1) && (mrow[min(jc1, N1 - 1)] != 0);

        const short* kp0 = kpB + (size_t)(j0 + lo) * DH + g * 8;
        short8 k00 = *(const short8*)(kp0);
        short8 k01 = *(const short8*)(kp0 + 32);
        short8 k10 = *(const short8*)(kp0 + 16 * DH);
        short8 k11 = *(const short8*)(kp0 + 16 * DH + 32);

        f32x4 s0 = __builtin_amdgcn_mfma_f32_16x16x32_bf16(qa0, k00, z, 0, 0, 0);
        s0 = __builtin_amdgcn_mfma_f32_16x16x32_bf16(qa1, k01, s0, 0, 0, 0);
        f32x4 s1 = __builtin_amdgcn_mfma_f32_16x16x32_bf16(qa0, k10, z, 0, 0, 0);
        s1 = __builtin_amdgcn_mfma_f32_16x16x32_bf16(qa1, k11, s1, 0, 0, 0);

        float mx[4];
        for (int r = 0; r < 4; r++) {
            float v0 = mk0 ? s0[r] * 0.125f : -1e30f;
            float v1 = mk1 ? s1[r] * 0.125f : -1e30f;
            s0[r] = v0; s1[r] = v1;
            mx[r] = fmaxf(v0, v1);
        }
        for (int off = 1; off < 16; off <<= 1)
            for (int r = 0; r < 4; r++)
                mx[r] = fmaxf(mx[r], __shfl_xor(mx[r], off));

        float al[4];
        for (int r = 0; r < 4; r++) {
            float mn = fmaxf(m_r[r], mx[r]);
            al[r] = __expf(m_r[r] - mn);
            m_r[r] = mn;
            float p0 = mk0 ? __expf(s0[r] - mn) : 0.f;
            float p1 = mk1 ? __expf(s1[r] - mn) : 0.f;
            s0[r] = p0; s1[r] = p1;
        }
        float rs[4];
        for (int r = 0; r < 4; r++) rs[r] = s0[r] + s1[r];
        for (int off = 1; off < 16; off <<= 1)
            for (int r = 0; r < 4; r++)
                rs[r] += __shfl_xor(rs[r], off);

        for (int r = 0; r < 4; r++) {
            l_r[r] = l_r[r] * al[r] + rs[r];
            o0[r] *= al[r]; o1[r] *= al[r]; o2[r] *= al[r]; o3[r] *= al[r];
            plds[w][g * 4 + r][lo] = f2bf(s0[r]);
            plds[w][g * 4 + r][16 + lo] = f2bf(s1[r]);
        }
        asm volatile("s_waitcnt lgkmcnt(0)" ::: "memory");
        short8 pa = *(const short8*)&plds[w][lo][g * 8];

        const short* vp = vpB + (size_t)lo * N1P + j0 + g * 8;
        o0 = __builtin_amdgcn_mfma_f32_16x16x32_bf16(pa, *(const short8*)(vp), o0, 0, 0, 0);
        o1 = __builtin_amdgcn_mfma_f32_16x16x32_bf16(pa, *(const short8*)(vp + 16 * N1P), o1, 0, 0, 0);
        o2 = __builtin_amdgcn_mfma_f32_16x16x32_bf16(pa, *(const short8*)(vp + 32 * N1P), o2, 0, 0, 0);
        o3 = __builtin_amdgcn_mfma_f32_16x16x32_bf16(pa, *(const short8*)(vp + 48 * N1P), o3, 0, 0, 0);
    }

    short* op = ob + ((size_t)(b * N_TOK) + q0) * INNER + h * DH;
    for (int r = 0; r < 4; r++) {
        float inv = 1.f / l_r[r];
        int row = g * 4 + r;
        short* o = op + (size_t)row * INNER;
        o[lo]      = f2bf(o0[r] * inv);
        o[16 + lo] = f2bf(o1[r] * inv);
        o[32 + lo] = f2bf(o2[r] * inv);
        o[48 + lo] = f2bf(o3[r] * inv);
    }
}

extern "C" void kernel_launch(void* const* d_in, const int* in_sizes, int n_in,
                              void* d_out, int out_size, void* d_ws, size_t ws_size,
                              hipStream_t stream) {
    const float* x    = (const float*)d_in[0];
    const float* ctx  = (const float*)d_in[1];
    const int*   mask = (const int*)d_in[2];
    const float* Wq   = (const float*)d_in[3];
    const float* Wk   = (const float*)d_in[4];
    const float* Wv   = (const float*)d_in[5];
    const float* Wkbg = (const float*)d_in[6];
    const float* Wvbg = (const float*)d_in[7];
    const float* Wout = (const float*)d_in[8];
    const float* bout = (const float*)d_in[9];
    float* out = (float*)d_out;

    char* p = (char*)d_ws;
    auto alloc = [&](size_t b) { char* r = p; p += (b + 255) & ~(size_t)255; return r; };
    short* x_bf  = (short*)alloc((size_t)BATCH * N_TOK * QDIM * 2);
    short* c_bf  = (short*)alloc((size_t)BATCH * N_TOK * CDIM * 2);
    short* Wqt   = (short*)alloc((size_t)INNER * QDIM * 2);
    short* Wkt   = (short*)alloc((size_t)INNER * CDIM * 2);
    short* Wvt   = (short*)alloc((size_t)INNER * CDIM * 2);
    short* Wot   = (short*)alloc((size_t)QDIM * INNER * 2);
    short* q_bf  = (short*)alloc((size_t)BATCH * NH * N_TOK * DH * 2);
    short* k_bf  = (short*)alloc((size_t)BATCH * NH * N1P * DH * 2);
    short* v_tmp = (short*)alloc((size_t)BATCH * NH * N1P * DH * 2);
    short* vt_bf = (short*)alloc((size_t)BATCH * NH * DH * N1P * 2);
    short* o_bf  = (short*)alloc((size_t)BATCH * N_TOK * INNER * 2);
    float* part  = (float*)alloc((size_t)BATCH * 32 * QDIM * 4);

    int n4 = BATCH * N_TOK * QDIM / 4;
    cast_bf16_kernel<<<(n4 + 255) / 256, 256, 0, stream>>>(x, x_bf, n4);
    cast_bf16_kernel<<<(n4 + 255) / 256, 256, 0, stream>>>(ctx, c_bf, n4);

    transpose_cast_kernel<<<dim3(INNER / 32, QDIM / 32), 256, 0, stream>>>(Wq, Wqt, QDIM, INNER);
    transpose_cast_kernel<<<dim3(INNER / 32, CDIM / 32), 256, 0, stream>>>(Wk, Wkt, CDIM, INNER);
    transpose_cast_kernel<<<dim3(INNER / 32, CDIM / 32), 256, 0, stream>>>(Wv, Wvt, CDIM, INNER);
    transpose_cast_kernel<<<dim3(QDIM / 32, INNER / 32), 256, 0, stream>>>(Wout, Wot, INNER, QDIM);

    pool_partial_kernel<<<dim3(32, BATCH), 256, 0, stream>>>(x, part);

    gemm_kernel<0><<<dim3(64, 4), 256, 0, stream>>>(x_bf, Wqt, q_bf, nullptr, nullptr,
                                                    BATCH * N_TOK, QDIM);
    gemm_kernel<1><<<dim3(64, 4), 256, 0, stream>>>(c_bf, Wkt, k_bf, nullptr, nullptr,
                                                    BATCH * N_TOK, CDIM);
    gemm_kernel<1><<<dim3(64, 4), 256, 0, stream>>>(c_bf, Wvt, v_tmp, nullptr, nullptr,
                                                    BATCH * N_TOK, CDIM);

    bg_kernel<<<BATCH, 256, 0, stream>>>(part, Wkbg, Wvbg, k_bf, v_tmp);
    transpose_v_kernel<<<dim3(N1P / 32, 1, BATCH * NH), 256, 0, stream>>>(v_tmp, vt_bf);

    attn_kernel<<<dim3(N_TOK / 64, NH, BATCH), 256, 0, stream>>>(q_bf, k_bf, vt_bf, mask, o_bf);

    gemm_kernel<2><<<dim3(64, 8), 256, 0, stream>>>(o_bf, Wot, nullptr, out, bout,
                                                    BATCH * N_TOK, INNER);
}

// Round 2
// 630.143 us; speedup vs baseline: 1.2125x; 1.2125x over previous
//
#include <hip/hip_runtime.h>
#include <stdint.h>

#define N_TOK 4096
#define QDIM  1024
#define CDIM  1024
#define NH    8
#define DH    64
#define INNER 512
#define BATCH 2
#define N1    4097   // keys incl. background row
#define N1P   4128   // padded to /32
#define NJB   129    // N1P/32
#define VROWS 80     // 64 V dims + mask row + 15 unused

typedef __attribute__((ext_vector_type(8))) short short8;
typedef __attribute__((ext_vector_type(4))) float f32x4;

__device__ __forceinline__ short f2bf(float f) {
    union { float f; uint32_t u; } x; x.f = f;
    uint32_t r = x.u + 0x7fffu + ((x.u >> 16) & 1u);   // RNE
    return (short)(r >> 16);
}

__device__ __forceinline__ void async_copy16(void* lds, const void* g) {
    __builtin_amdgcn_global_load_lds(
        (const __attribute__((address_space(1))) void*)g,
        (__attribute__((address_space(3))) void*)lds, 16, 0, 0);
}

// ---------------- cast fp32 -> bf16 (vectorized) ----------------
__global__ __launch_bounds__(256) void cast_bf16_kernel(
        const float* __restrict__ s, short* __restrict__ d, int n4) {
    int i = blockIdx.x * 256 + threadIdx.x;
    if (i >= n4) return;
    float4 v = ((const float4*)s)[i];
    short4 o = make_short4(f2bf(v.x), f2bf(v.y), f2bf(v.z), f2bf(v.w));
    ((short4*)d)[i] = o;
}

// ------ weight transpose-cast: W[K][N] f32 -> Wt[N][K] bf16, optional scale ------
__global__ __launch_bounds__(256) void transpose_cast_kernel(
        const float* __restrict__ W, short* __restrict__ Wt, int K, int N,
        float scale) {
    __shared__ float tile[32][33];
    int n0 = blockIdx.x * 32, k0 = blockIdx.y * 32;
    int tx = threadIdx.x & 31, ty = threadIdx.x >> 5;       // ty 0..7
    for (int r = ty; r < 32; r += 8)
        tile[r][tx] = W[(size_t)(k0 + r) * N + n0 + tx];
    __syncthreads();
    for (int r = ty; r < 32; r += 8)
        Wt[(size_t)(n0 + r) * K + k0 + tx] = f2bf(tile[tx][r] * scale);
}

// ---------------- pooled mean stage 1: partial sums over 128-row chunks ----------------
__global__ __launch_bounds__(256) void pool_partial_kernel(
        const float* __restrict__ x, float* __restrict__ part) {
    int b = blockIdx.y, c = blockIdx.x;                     // c 0..31
    int t = threadIdx.x;
    float s0 = 0.f, s1 = 0.f, s2 = 0.f, s3 = 0.f;
    const float* xp = x + ((size_t)b * N_TOK + c * 128) * QDIM;
    for (int n = 0; n < 128; n++) {
        const float* row = xp + (size_t)n * QDIM;
        s0 += row[t];
        s1 += row[256 + t];
        s2 += row[512 + t];
        s3 += row[768 + t];
    }
    float* pp = part + ((size_t)b * 32 + c) * QDIM;
    pp[t] = s0; pp[256 + t] = s1; pp[512 + t] = s2; pp[768 + t] = s3;
}

// ------- stage 2: finish mean, fp32 bg projections (1 output/thread), k pads -------
__global__ __launch_bounds__(256) void bg_kernel(
        const float* __restrict__ part, const float* __restrict__ Wkbg,
        const float* __restrict__ Wvbg, short* __restrict__ kb, short* __restrict__ vb) {
    int b = blockIdx.x, jb = blockIdx.y, t = threadIdx.x;   // jb 0..3
    __shared__ float pooled[QDIM];
    for (int d = t; d < QDIM; d += 256) {
        float s = 0.f;
        for (int c = 0; c < 32; c++) s += part[((size_t)b * 32 + c) * QDIM + d];
        pooled[d] = s * (1.f / (float)N_TOK);
    }
    __syncthreads();
    int flat = jb * 256 + t;          // 0..1023
    int matv = flat >> 9;             // 0: k, 1: v
    int o = flat & 511;
    const float* W = matv ? Wvbg : Wkbg;
    float s = 0.f;
    for (int k = 0; k < QDIM; k++) s += pooled[k] * W[(size_t)k * INNER + o];
    int h = o >> 6, d = o & 63;
    short* dst = matv ? vb : kb;
    dst[(((size_t)(b * NH + h)) * N1P + N_TOK) * DH + d] = f2bf(s);
    if (jb == 0) {  // zero padding key rows 4097..4127 (K side must be finite)
        for (int idx = t; idx < NH * 31 * DH; idx += 256) {
            int h2 = idx / (31 * DH);
            int r2 = idx % (31 * DH);
            int j = N_TOK + 1 + r2 / DH;
            int d2 = r2 % DH;
            kb[(((size_t)(b * NH + h2)) * N1P + j) * DH + d2] = 0;
        }
    }
}

// ------- V transpose+permute+mask: [BH][N1P][64] -> tiled [BH][129][80][32] -------
// stored slot p within a 32-block holds key sigma(p) = (p>>1) + ((p&1)<<4);
// masked/pad keys: V column zeroed; row 64 = mask (bf16 1/0).
__global__ __launch_bounds__(256) void transpose_v_kernel(
        const short* __restrict__ vin, short* __restrict__ vout,
        const int* __restrict__ mask) {
    __shared__ short tile[32][65];
    __shared__ int mloc[32];
    int bh = blockIdx.z, b = bh >> 3;
    int j0 = blockIdx.x * 32, jb = blockIdx.x;
    int tx = threadIdx.x & 63, ty = threadIdx.x >> 6;       // ty 0..3
    const short* src = vin + (size_t)bh * N1P * DH;
    for (int r = ty; r < 32; r += 4)
        tile[r][tx] = src[(size_t)(j0 + r) * DH + tx];
    if (threadIdx.x < 32) {
        int j = j0 + threadIdx.x;
        mloc[threadIdx.x] = (j < N1) ? mask[b * N1 + j] : 0;
    }
    __syncthreads();
    int tp = threadIdx.x & 31, dy = threadIdx.x >> 5;       // dy 0..7
    int s = (tp >> 1) + ((tp & 1) << 4);                    // sigma(p)
    bool mk = mloc[s] != 0;
    short* dst = vout + ((size_t)bh * NJB + jb) * VROWS * 32;
    for (int d = dy; d < DH; d += 8)
        dst[d * 32 + tp] = mk ? tile[s][d] : (short)0;
    if (dy == 0) dst[64 * 32 + tp] = mk ? (short)0x3F80 : (short)0;  // bf16 1.0
}

// ---------------- fused QKV bf16 MFMA GEMM ----------------
// blocks 0..255: Q = x @ Wqt^T (scaled) -> q_bf [BH][4096][64]
// blocks 256..767: KV = ctx @ Wkvt^T -> k_bf / v_tmp [BH][N1P][64]
__global__ __launch_bounds__(256) void qkv_gemm_kernel(
        const short* __restrict__ x_bf, const short* __restrict__ c_bf,
        const short* __restrict__ Wqt, const short* __restrict__ Wkvt,
        short* __restrict__ q_bf, short* __restrict__ k_bf, short* __restrict__ v_tmp) {
    __shared__ short As[128 * 32];
    __shared__ short Bs[128 * 32];
    const int t = threadIdx.x;
    const int lane = t & 63, w = t >> 6;
    const int wr = w >> 1, wc = w & 1;
    const int lo = lane & 15, g = lane >> 4;
    const int arow = lane >> 2;
    const int ac8 = (lane & 3) * 8;

    const short *A, *W;
    int m0, n0, which;
    int bid = blockIdx.x;
    if (bid < 256) { A = x_bf; W = Wqt;  m0 = (bid >> 2) * 128; n0 = (bid & 3) * 128; which = 0; }
    else { int i = bid - 256; A = c_bf; W = Wkvt; m0 = (i >> 3) * 128; n0 = (i & 7) * 128;
           which = (n0 < 512) ? 1 : 2; }

    f32x4 acc[4][4] = {};
    for (int k0 = 0; k0 < 1024; k0 += 32) {
        for (int q = 0; q < 2; q++) {
            int seg = w * 2 + q;
            async_copy16(&As[seg * 512], A + (size_t)(m0 + seg * 16 + arow) * 1024 + k0 + ac8);
            async_copy16(&Bs[seg * 512], W + (size_t)(n0 + seg * 16 + arow) * 1024 + k0 + ac8);
        }
        __syncthreads();
        short8 af[4], bfv[4];
        for (int i = 0; i < 4; i++)
            af[i] = *(const short8*)&As[(wr * 64 + i * 16 + lo) * 32 + g * 8];
        for (int j = 0; j < 4; j++)
            bfv[j] = *(const short8*)&Bs[(wc * 64 + j * 16 + lo) * 32 + g * 8];
        for (int i = 0; i < 4; i++)
            for (int j = 0; j < 4; j++)
                acc[i][j] = __builtin_amdgcn_mfma_f32_16x16x32_bf16(af[i], bfv[j], acc[i][j], 0, 0, 0);
        __syncthreads();
    }

    short* dstb = (which == 0) ? q_bf : (which == 1) ? k_bf : v_tmp;
    int coloff = (which == 2) ? 512 : 0;
    size_t rowstride = (which == 0) ? N_TOK : N1P;
    for (int i = 0; i < 4; i++)
        for (int j = 0; j < 4; j++) {
            int row = m0 + wr * 64 + i * 16 + g * 4;
            int col = n0 - coloff + wc * 64 + j * 16 + lo;
            f32x4 v = acc[i][j];
            int h = col >> 6, d = col & 63;
            for (int r = 0; r < 4; r++) {
                int m = row + r;
                int b = m >> 12, ii = m & 4095;
                dstb[(((size_t)(b * NH + h)) * rowstride + ii) * DH + d] = f2bf(v[r]);
            }
        }
}

// ---------------- out-projection GEMM: out = O @ Wot^T + bias (f32) ----------------
__global__ __launch_bounds__(256) void out_gemm_kernel(
        const short* __restrict__ A, const short* __restrict__ Wt,
        float* __restrict__ outf, const float* __restrict__ bias) {
    __shared__ short As[128 * 32];
    __shared__ short Bs[128 * 32];
    const int t = threadIdx.x;
    const int lane = t & 63, w = t >> 6;
    const int wr = w >> 1, wc = w & 1;
    const int lo = lane & 15, g = lane >> 4;
    const int arow = lane >> 2;
    const int ac8 = (lane & 3) * 8;
    const int m0 = blockIdx.x * 128, n0 = blockIdx.y * 128;

    f32x4 acc[4][4] = {};
    for (int k0 = 0; k0 < INNER; k0 += 32) {
        for (int q = 0; q < 2; q++) {
            int seg = w * 2 + q;
            async_copy16(&As[seg * 512], A + (size_t)(m0 + seg * 16 + arow) * INNER + k0 + ac8);
            async_copy16(&Bs[seg * 512], Wt + (size_t)(n0 + seg * 16 + arow) * INNER + k0 + ac8);
        }
        __syncthreads();
        short8 af[4], bfv[4];
        for (int i = 0; i < 4; i++)
            af[i] = *(const short8*)&As[(wr * 64 + i * 16 + lo) * 32 + g * 8];
        for (int j = 0; j < 4; j++)
            bfv[j] = *(const short8*)&Bs[(wc * 64 + j * 16 + lo) * 32 + g * 8];
        for (int i = 0; i < 4; i++)
            for (int j = 0; j < 4; j++)
                acc[i][j] = __builtin_amdgcn_mfma_f32_16x16x32_bf16(af[i], bfv[j], acc[i][j], 0, 0, 0);
        __syncthreads();
    }
    for (int i = 0; i < 4; i++)
        for (int j = 0; j < 4; j++) {
            int row = m0 + wr * 64 + i * 16 + g * 4;
            int col = n0 + wc * 64 + j * 16 + lo;
            f32x4 v = acc[i][j];
            for (int r = 0; r < 4; r++)
                outf[(size_t)(row + r) * QDIM + col] = v[r] + bias[col];
        }
}

// ---------------- flash attention, shift-free exp2 softmax ----------------
// grid (64, 8, 2), 256 threads; wave w owns 16 Q rows. No barriers in loop.
__global__ __launch_bounds__(256) void attn_kernel(
        const short* __restrict__ qb,   // [BH][4096][64], scaled by 0.125*log2e via Wq
        const short* __restrict__ kb,   // [BH][N1P][64]
        const short* __restrict__ vtb,  // [BH][129][80][32], permuted cols, masked, row64=mask
        short* __restrict__ ob) {       // [B*4096][512]
    const int t = threadIdx.x, lane = t & 63, w = t >> 6;
    const int lo = lane & 15, g = lane >> 4;
    const int b = blockIdx.z, h = blockIdx.y;
    const int q0 = blockIdx.x * 64 + w * 16;
    const size_t bh = (size_t)(b * NH + h);

    const short* qp = qb + (bh * N_TOK + q0 + lo) * DH;
    short8 qa0 = *(const short8*)(qp + g * 8);
    short8 qa1 = *(const short8*)(qp + 32 + g * 8);

    const short* kp = kb + bh * N1P * DH + (size_t)lo * DH + g * 8;
    // per-lane V base: +1024B bias so frag offsets (f-1)*1024 stay in imm range
    const short* vp = vtb + bh * NJB * VROWS * 32 + (size_t)lo * 32 + g * 8 + 512;

    f32x4 o0 = {}, o1 = {}, o2 = {}, o3 = {}, o4 = {};
    f32x4 z = {};
    __shared__ short plds[4][16 * 40];
    uint32_t* pwr = (uint32_t*)&plds[w][0];
    const int wbase = g * 4 * 20 + lo;                 // dword index for r=0
    const short* prd = &plds[w][lo * 40 + g * 8];

    for (int jb = 0; jb < NJB; jb++) {
        short8 k00 = *(const short8*)(kp);
        short8 k01 = *(const short8*)(kp + 32);
        short8 k10 = *(const short8*)(kp + 16 * DH);
        short8 k11 = *(const short8*)(kp + 16 * DH + 32);
        kp += 32 * DH;

        f32x4 s0 = __builtin_amdgcn_mfma_f32_16x16x32_bf16(qa0, k00, z, 0, 0, 0);
        s0 = __builtin_amdgcn_mfma_f32_16x16x32_bf16(qa1, k01, s0, 0, 0, 0);
        f32x4 s1 = __builtin_amdgcn_mfma_f32_16x16x32_bf16(qa0, k10, z, 0, 0, 0);
        s1 = __builtin_amdgcn_mfma_f32_16x16x32_bf16(qa1, k11, s1, 0, 0, 0);

        // p = 2^s (shift-free: |s| bounded), round-half-up to bf16, pack pairs
        for (int r = 0; r < 4; r++) {
            float p0 = __builtin_amdgcn_exp2f(s0[r]);
            float p1 = __builtin_amdgcn_exp2f(s1[r]);
            uint32_t u0 = __float_as_uint(p0) + 0x8000u;
            uint32_t u1 = __float_as_uint(p1) + 0x8000u;
            pwr[wbase + r * 20] = __builtin_amdgcn_perm(u1, u0, 0x07060302u);
        }
        asm volatile("s_waitcnt lgkmcnt(0)" ::: "memory");
        short8 pa = *(const short8*)prd;

        o0 = __builtin_amdgcn_mfma_f32_16x16x32_bf16(pa, *(const short8*)(vp - 512), o0, 0, 0, 0);
        o1 = __builtin_amdgcn_mfma_f32_16x16x32_bf16(pa, *(const short8*)(vp), o1, 0, 0, 0);
        o2 = __builtin_amdgcn_mfma_f32_16x16x32_bf16(pa, *(const short8*)(vp + 512), o2, 0, 0, 0);
        o3 = __builtin_amdgcn_mfma_f32_16x16x32_bf16(pa, *(const short8*)(vp + 1024), o3, 0, 0, 0);
        o4 = __builtin_amdgcn_mfma_f32_16x16x32_bf16(pa, *(const short8*)(vp + 1536), o4, 0, 0, 0);
        vp += VROWS * 32;
    }

    short* op = ob + ((size_t)(b * N_TOK) + q0) * INNER + h * DH;
    for (int r = 0; r < 4; r++) {
        float l = __shfl(o4[r], lane & 48);            // col 0 of frag4 = sum(p*mask)
        float inv = (l > 0.f) ? 1.f / l : 0.f;
        short* o = op + (size_t)(g * 4 + r) * INNER;
        o[lo]      = f2bf(o0[r] * inv);
        o[16 + lo] = f2bf(o1[r] * inv);
        o[32 + lo] = f2bf(o2[r] * inv);
        o[48 + lo] = f2bf(o3[r] * inv);
    }
}

extern "C" void kernel_launch(void* const* d_in, const int* in_sizes, int n_in,
                              void* d_out, int out_size, void* d_ws, size_t ws_size,
                              hipStream_t stream) {
    const float* x    = (const float*)d_in[0];
    const float* ctx  = (const float*)d_in[1];
    const int*   mask = (const int*)d_in[2];
    const float* Wq   = (const float*)d_in[3];
    const float* Wk   = (const float*)d_in[4];
    const float* Wv   = (const float*)d_in[5];
    const float* Wkbg = (const float*)d_in[6];
    const float* Wvbg = (const float*)d_in[7];
    const float* Wout = (const float*)d_in[8];
    const float* bout = (const float*)d_in[9];
    float* out = (float*)d_out;

    char* p = (char*)d_ws;
    auto alloc = [&](size_t b) { char* r = p; p += (b + 255) & ~(size_t)255; return r; };
    short* x_bf  = (short*)alloc((size_t)BATCH * N_TOK * QDIM * 2);
    short* c_bf  = (short*)alloc((size_t)BATCH * N_TOK * CDIM * 2);
    short* Wqt   = (short*)alloc((size_t)INNER * QDIM * 2);
    short* Wkvt  = (short*)alloc((size_t)2 * INNER * CDIM * 2);   // Wk | Wv transposed
    short* Wot   = (short*)alloc((size_t)QDIM * INNER * 2);
    short* q_bf  = (short*)alloc((size_t)BATCH * NH * N_TOK * DH * 2);
    short* k_bf  = (short*)alloc((size_t)BATCH * NH * N1P * DH * 2);
    short* v_tmp = (short*)alloc((size_t)BATCH * NH * N1P * DH * 2);
    short* vt_bf = (short*)alloc((size_t)BATCH * NH * NJB * VROWS * 32 * 2);
    short* o_bf  = (short*)alloc((size_t)BATCH * N_TOK * INNER * 2);
    float* part  = (float*)alloc((size_t)BATCH * 32 * QDIM * 4);

    const float SCALE_Q = 0.125f * 1.4426950408889634f;  // fold scale*log2(e) into Wq

    int n4 = BATCH * N_TOK * QDIM / 4;
    cast_bf16_kernel<<<(n4 + 255) / 256, 256, 0, stream>>>(x, x_bf, n4);
    cast_bf16_kernel<<<(n4 + 255) / 256, 256, 0, stream>>>(ctx, c_bf, n4);

    transpose_cast_kernel<<<dim3(INNER / 32, QDIM / 32), 256, 0, stream>>>(Wq, Wqt, QDIM, INNER, SCALE_Q);
    transpose_cast_kernel<<<dim3(INNER / 32, CDIM / 32), 256, 0, stream>>>(Wk, Wkvt, CDIM, INNER, 1.f);
    transpose_cast_kernel<<<dim3(INNER / 32, CDIM / 32), 256, 0, stream>>>(Wv, Wkvt + (size_t)INNER * CDIM, CDIM, INNER, 1.f);
    transpose_cast_kernel<<<dim3(QDIM / 32, INNER / 32), 256, 0, stream>>>(Wout, Wot, INNER, QDIM, 1.f);

    pool_partial_kernel<<<dim3(32, BATCH), 256, 0, stream>>>(x, part);

    qkv_gemm_kernel<<<768, 256, 0, stream>>>(x_bf, c_bf, Wqt, Wkvt, q_bf, k_bf, v_tmp);

    bg_kernel<<<dim3(BATCH, 4), 256, 0, stream>>>(part, Wkbg, Wvbg, k_bf, v_tmp);
    transpose_v_kernel<<<dim3(NJB, 1, BATCH * NH), 256, 0, stream>>>(v_tmp, vt_bf, mask);

    attn_kernel<<<dim3(N_TOK / 64, NH, BATCH), 256, 0, stream>>>(q_bf, k_bf, vt_bf, o_bf);

    out_gemm_kernel<<<dim3(64, 8), 256, 0, stream>>>(o_bf, Wot, out, bout);
}